// Round 2
// baseline (514.734 us; speedup 1.0000x reference)
//
#include <hip/hip_runtime.h>
#include <math.h>

#define DIM    4096
#define NE     64
#define M_TOK  16384   // B*S
#define BK     32
#define LD     68      // LDS row stride (floats): %4==0 -> b128-aligned, %32==4 -> spreads banks

// ---------------------------------------------------------------------------
// Fused kernel: per 64-token tile, full-K fp32 GEMM (64 tok x 64 exp) with
// double-buffered transposed LDS tiles, then in-kernel top-2 / softmax /
// usage / z-loss epilogue. One block per 64 tokens, 256 threads (4 waves).
// ---------------------------------------------------------------------------
__global__ __launch_bounds__(256) void moe_fused(
    const float* __restrict__ x, const float* __restrict__ W,
    float* __restrict__ out_w, float* __restrict__ out_idx,
    float* __restrict__ out_usage, float* __restrict__ z_acc,
    float* __restrict__ out_probs)
{
    __shared__ float Xs[2][BK][LD];
    __shared__ float Ws[2][BK][LD];
    __shared__ float Ls[64][LD];
    __shared__ float us[4][NE];
    __shared__ float zs[4];

    const int tid  = threadIdx.x;
    const int tx   = tid & 15;    // expert group (4 experts)
    const int ty   = tid >> 4;    // token group (4 tokens)
    const int tok0 = blockIdx.x * 64;

    // staging map: thread -> (row 0..31 [+32], k-group 0..7)
    const int srow = tid >> 3;
    const int sc4  = tid & 7;
    const float* xbase = x + (size_t)(tok0 + srow) * DIM + sc4 * 4;
    const float* wbase = W + (size_t)srow * DIM + sc4 * 4;

    float acc[4][4] = {};

    // ---- prologue: stage kt=0 into buf 0 (transposed)
    {
        const float4 xv0 = *(const float4*)(xbase);
        const float4 xv1 = *(const float4*)(xbase + 32 * DIM);
        const float4 wv0 = *(const float4*)(wbase);
        const float4 wv1 = *(const float4*)(wbase + 32 * DIM);
        #pragma unroll
        for (int q = 0; q < 4; ++q) {
            Xs[0][sc4 * 4 + q][srow]      = ((const float*)&xv0)[q];
            Xs[0][sc4 * 4 + q][srow + 32] = ((const float*)&xv1)[q];
            Ws[0][sc4 * 4 + q][srow]      = ((const float*)&wv0)[q];
            Ws[0][sc4 * 4 + q][srow + 32] = ((const float*)&wv1)[q];
        }
    }
    __syncthreads();

    int buf = 0;
    for (int kt = 0; kt < DIM; kt += BK) {
        float4 xv0, xv1, wv0, wv1;
        const bool next = (kt + BK) < DIM;
        if (next) {                       // issue next tile's loads early
            const float* xp = xbase + kt + BK;
            const float* wp = wbase + kt + BK;
            xv0 = *(const float4*)(xp);
            xv1 = *(const float4*)(xp + 32 * DIM);
            wv0 = *(const float4*)(wp);
            wv1 = *(const float4*)(wp + 32 * DIM);
        }

        #pragma unroll
        for (int kk = 0; kk < BK; ++kk) {
            const float4 a4 = *(const float4*)&Xs[buf][kk][ty * 4];
            const float4 b4 = *(const float4*)&Ws[buf][kk][tx * 4];
            const float a[4] = {a4.x, a4.y, a4.z, a4.w};
            const float b[4] = {b4.x, b4.y, b4.z, b4.w};
            #pragma unroll
            for (int i = 0; i < 4; ++i)
                #pragma unroll
                for (int j = 0; j < 4; ++j)
                    acc[i][j] = fmaf(a[i], b[j], acc[i][j]);
        }

        if (next) {                       // write into the other buffer
            const int nb = buf ^ 1;
            #pragma unroll
            for (int q = 0; q < 4; ++q) {
                Xs[nb][sc4 * 4 + q][srow]      = ((const float*)&xv0)[q];
                Xs[nb][sc4 * 4 + q][srow + 32] = ((const float*)&xv1)[q];
                Ws[nb][sc4 * 4 + q][srow]      = ((const float*)&wv0)[q];
                Ws[nb][sc4 * 4 + q][srow + 32] = ((const float*)&wv1)[q];
            }
        }
        __syncthreads();
        buf ^= 1;
    }

    // ---- dump accumulators to LDS so each wave can see whole token rows
    #pragma unroll
    for (int i = 0; i < 4; ++i) {
        *(float4*)&Ls[ty * 4 + i][tx * 4] =
            make_float4(acc[i][0], acc[i][1], acc[i][2], acc[i][3]);
    }
    __syncthreads();

    // ---- epilogue: one wave per 16 tokens, lane = expert
    const int lane = tid & 63;
    const int w    = tid >> 6;

    float local_usage = 0.f;
    float local_z     = 0.f;

    for (int i = 0; i < 16; ++i) {
        const int tl = w * 16 + i;
        const int t  = tok0 + tl;
        const float v = Ls[tl][lane];

        // argmax (tie-break lower index, matching jax.lax.top_k)
        float m = v; int mi = lane;
        #pragma unroll
        for (int off = 32; off >= 1; off >>= 1) {
            const float om = __shfl_xor(m, off);
            const int   oi = __shfl_xor(mi, off);
            if (om > m || (om == m && oi < mi)) { m = om; mi = oi; }
        }
        const float m1 = m; const int i1 = mi;

        // second max, excluding argmax lane
        float m2 = (lane == i1) ? -INFINITY : v; int mi2 = lane;
        #pragma unroll
        for (int off = 32; off >= 1; off >>= 1) {
            const float om = __shfl_xor(m2, off);
            const int   oi = __shfl_xor(mi2, off);
            if (om > m2 || (om == m2 && oi < mi2)) { m2 = om; mi2 = oi; }
        }

        // softmax over all 64 experts
        const float e = expf(v - m1);
        float s = e;
        #pragma unroll
        for (int off = 32; off >= 1; off >>= 1) s += __shfl_xor(s, off);
        const float p = e / s;
        out_probs[(size_t)t * NE + lane] = p;
        local_usage += p;

        const float lse = m1 + logf(s);
        local_z += lse * lse;

        if (lane == 0) {
            const float d   = expf(m2 - m1);
            const float inv = 1.f / (1.f + d);
            out_w[t * 2]       = inv;           // softmax([m1, m2])
            out_w[t * 2 + 1]   = d * inv;
            out_idx[t * 2]     = (float)i1;     // indices as float values
            out_idx[t * 2 + 1] = (float)mi2;
        }
    }

    // ---- block reductions, one atomic set per block
    us[w][lane] = local_usage;
    if (lane == 0) zs[w] = local_z;
    __syncthreads();
    if (tid < NE) {
        const float su = us[0][tid] + us[1][tid] + us[2][tid] + us[3][tid];
        atomicAdd(&out_usage[tid], su);
    }
    if (tid == 0) atomicAdd(z_acc, zs[0] + zs[1] + zs[2] + zs[3]);
}

// ---------------------------------------------------------------------------
__global__ void finalize(float* usage, float* lb, float* z)
{
    const int e = threadIdx.x;   // 64 threads
    const float u = usage[e] * (1.f / (float)M_TOK);
    usage[e] = u;
    float s = u * u;
    #pragma unroll
    for (int off = 32; off >= 1; off >>= 1) s += __shfl_xor(s, off);
    if (e == 0) {
        lb[0] = s * (float)NE;
        z[0]  = z[0] * (1.f / (float)M_TOK);
    }
}

// ---------------------------------------------------------------------------
extern "C" void kernel_launch(void* const* d_in, const int* in_sizes, int n_in,
                              void* d_out, int out_size, void* d_ws, size_t ws_size,
                              hipStream_t stream)
{
    const float* x = (const float*)d_in[0];
    const float* W = (const float*)d_in[1];
    float* o = (float*)d_out;

    // output layout (flat fp32, reference return order):
    float* out_w     = o;            // [16384][2]
    float* out_idx   = o + 32768;    // [16384][2] (as floats)
    float* out_lb    = o + 65536;    // scalar
    float* out_z     = o + 65537;    // scalar
    float* out_usage = o + 65538;    // [64]
    float* out_probs = o + 65602;    // [16384][64]

    // zero the atomic accumulators: z (1) + usage (64)
    hipMemsetAsync(out_z, 0, 65 * sizeof(float), stream);

    moe_fused<<<M_TOK / 64, 256, 0, stream>>>(x, W, out_w, out_idx,
                                              out_usage, out_z, out_probs);
    finalize<<<1, 64, 0, stream>>>(out_usage, out_lb, out_z);
}